// Round 1
// baseline (503.310 us; speedup 1.0000x reference)
//
#include <hip/hip_runtime.h>

// WaveMaskEncoder: x(16,128,128,128) --EN--> enc(16,48,48,48) --DE--> out(16,128,128,128)
// The three decode orders in the reference are mathematically identical
// (contractions along distinct axes commute), so we compute one chain.
//
// All stages: thread owns a coalesced output lane, loops the contraction axis,
// weight address is wave-uniform -> compiler scalarizes to s_load (scalar pipe),
// inner loop is pure v_fma_f32 with SGPR weight operand.

#define LDIM 128
#define NDIM 48
#define HW   (LDIM * LDIM)     // 16384
#define L3   (LDIM * HW)       // 2097152
#define BCN  16

// Stage A: t1[bc,p,h,w] = sum_d x[bc,d,h,w] * EN3[d,p]
__global__ __launch_bounds__(256) void kA(const float* __restrict__ x,
                                          const float* __restrict__ EN3,
                                          float* __restrict__ t1) {
    const int bc = blockIdx.y;
    const int hw = blockIdx.x * 256 + threadIdx.x;
    const float* xp = x + (size_t)bc * L3 + hw;
    float acc[NDIM];
#pragma unroll
    for (int p = 0; p < NDIM; ++p) acc[p] = 0.f;
    for (int d = 0; d < LDIM; ++d) {
        float v = xp[(size_t)d * HW];
        const float* wd = EN3 + d * NDIM;   // wave-uniform -> s_load
#pragma unroll
        for (int p = 0; p < NDIM; ++p) acc[p] = fmaf(v, wd[p], acc[p]);
    }
    float* op = t1 + (size_t)bc * (NDIM * HW) + hw;
#pragma unroll
    for (int p = 0; p < NDIM; ++p) op[(size_t)p * HW] = acc[p];
}

// Stage B: t2[bc,p,q,w] = sum_h t1[bc,p,h,w] * EN2[h,q]
__global__ __launch_bounds__(128) void kB(const float* __restrict__ t1,
                                          const float* __restrict__ EN2,
                                          float* __restrict__ t2) {
    const int bp = blockIdx.x;          // 0..767 = bc*48+p
    const int w  = threadIdx.x;         // 0..127
    const float* ip = t1 + (size_t)bp * HW + w;
    float acc[NDIM];
#pragma unroll
    for (int q = 0; q < NDIM; ++q) acc[q] = 0.f;
    for (int h = 0; h < LDIM; ++h) {
        float v = ip[h * LDIM];
        const float* wh = EN2 + h * NDIM;
#pragma unroll
        for (int q = 0; q < NDIM; ++q) acc[q] = fmaf(v, wh[q], acc[q]);
    }
    float* op = t2 + (size_t)bp * (NDIM * LDIM) + w;
#pragma unroll
    for (int q = 0; q < NDIM; ++q) op[q * LDIM] = acc[q];
}

// Stage C: enc[bc,p,q,r] = sum_w t2[bc,p,q,w] * EN1[w,r]
// contraction over the contiguous axis: per-thread float4 row reads,
// weights still wave-uniform (w,r are loop indices).
__global__ __launch_bounds__(256) void kC(const float* __restrict__ t2,
                                          const float* __restrict__ EN1,
                                          float* __restrict__ enc) {
    const int m = blockIdx.x * 256 + threadIdx.x;   // 0..36863 = bc*48*48 + ...
    const float4* row = (const float4*)(t2 + (size_t)m * LDIM);
    float acc[NDIM];
#pragma unroll
    for (int r = 0; r < NDIM; ++r) acc[r] = 0.f;
    for (int w4 = 0; w4 < LDIM / 4; ++w4) {
        float4 v = row[w4];
        const float* w0 = EN1 + (w4 * 4) * NDIM;
#pragma unroll
        for (int r = 0; r < NDIM; ++r) {
            acc[r] = fmaf(v.x, w0[r],            acc[r]);
            acc[r] = fmaf(v.y, w0[NDIM + r],     acc[r]);
            acc[r] = fmaf(v.z, w0[2 * NDIM + r], acc[r]);
            acc[r] = fmaf(v.w, w0[3 * NDIM + r], acc[r]);
        }
    }
    float4* op = (float4*)(enc + (size_t)m * NDIM);
#pragma unroll
    for (int r4 = 0; r4 < NDIM / 4; ++r4)
        op[r4] = make_float4(acc[4 * r4], acc[4 * r4 + 1], acc[4 * r4 + 2], acc[4 * r4 + 3]);
}

// Stage D: u1[bc,p,q,w] = sum_r enc[bc,p,q,r] * DE1[r,w]
// DE1 column cached in registers per lane; enc row is wave-uniform -> s_load.
__global__ __launch_bounds__(256) void kD(const float* __restrict__ enc,
                                          const float* __restrict__ DE1,
                                          float* __restrict__ u1) {
    const int bp = blockIdx.x;               // 0..767
    const int w  = threadIdx.x & (LDIM - 1);
    const int qh = threadIdx.x >> 7;         // 0/1, wave-uniform
    float de1col[NDIM];
#pragma unroll
    for (int r = 0; r < NDIM; ++r) de1col[r] = DE1[r * LDIM + w];
    const float* eb = enc + (size_t)bp * (NDIM * NDIM);
    float* ob = u1 + (size_t)bp * (NDIM * LDIM) + w;
    for (int q = qh; q < NDIM; q += 2) {
        const float* er = eb + q * NDIM;     // wave-uniform -> s_load
        float s = 0.f;
#pragma unroll
        for (int r = 0; r < NDIM; ++r) s = fmaf(er[r], de1col[r], s);
        ob[q * LDIM] = s;
    }
}

// Stage E: u2[bc,p,h,w] = sum_q u1[bc,p,q,w] * DE2[q,h]
__global__ __launch_bounds__(256) void kE(const float* __restrict__ u1,
                                          const float* __restrict__ DE2,
                                          float* __restrict__ u2) {
    const int bp = blockIdx.y;               // 0..767
    const int w  = threadIdx.x & (LDIM - 1);
    const int h0 = (blockIdx.x * 2 + (threadIdx.x >> 7)) * 32;  // wave-uniform
    const float* ip = u1 + (size_t)bp * (NDIM * LDIM) + w;
    float acc[32];
#pragma unroll
    for (int j = 0; j < 32; ++j) acc[j] = 0.f;
    for (int q = 0; q < NDIM; ++q) {
        float v = ip[q * LDIM];
        const float* wq = DE2 + q * LDIM + h0;   // wave-uniform -> s_load
#pragma unroll
        for (int j = 0; j < 32; ++j) acc[j] = fmaf(v, wq[j], acc[j]);
    }
    float* op = u2 + (size_t)bp * HW + w;
#pragma unroll
    for (int j = 0; j < 32; ++j) op[(h0 + j) * LDIM] = acc[j];
}

// Stage F: out[bc,d,h,w] = sum_p u2[bc,p,h,w] * DE3[p,d]
__global__ __launch_bounds__(256) void kF(const float* __restrict__ u2,
                                          const float* __restrict__ DE3,
                                          float* __restrict__ out) {
    const int bc = blockIdx.y;               // 0..15
    const int hw = blockIdx.x * 256 + threadIdx.x;
    const int d0 = blockIdx.z * 32;
    const float* ip = u2 + (size_t)bc * (NDIM * HW) + hw;
    float acc[32];
#pragma unroll
    for (int j = 0; j < 32; ++j) acc[j] = 0.f;
    for (int p = 0; p < NDIM; ++p) {
        float v = ip[(size_t)p * HW];
        const float* wp = DE3 + p * LDIM + d0;   // wave-uniform -> s_load
#pragma unroll
        for (int j = 0; j < 32; ++j) acc[j] = fmaf(v, wp[j], acc[j]);
    }
    float* op = out + (size_t)bc * L3 + hw;
#pragma unroll
    for (int j = 0; j < 32; ++j) op[(size_t)(d0 + j) * HW] = acc[j];
}

extern "C" void kernel_launch(void* const* d_in, const int* in_sizes, int n_in,
                              void* d_out, int out_size, void* d_ws, size_t ws_size,
                              hipStream_t stream) {
    const float* x   = (const float*)d_in[0];
    const float* EN3 = (const float*)d_in[1];
    const float* EN2 = (const float*)d_in[2];
    const float* EN1 = (const float*)d_in[3];
    const float* DE3 = (const float*)d_in[4];
    const float* DE2 = (const float*)d_in[5];
    const float* DE1 = (const float*)d_in[6];
    float* out = (float*)d_out;
    float* ws  = (float*)d_ws;

    // Workspace layout (floats), 76.3 MB total with region reuse:
    //   seg0 [0, 12582912)            : t1 (A->B), then u2 (E->F)
    //   seg1 [12582912, 17301504)     : t2 (B->C), then u1 (D->E)
    //   seg2 [17301504, 19070976)     : enc (C->D)
    float* t1  = ws;
    float* t2  = ws + 12582912;
    float* enc = ws + 12582912 + 4718592;
    float* u1  = t2;   // t2 dead after C
    float* u2  = t1;   // t1 dead after B

    kA<<<dim3(64, 16),    256, 0, stream>>>(x,  EN3, t1);
    kB<<<dim3(768),       128, 0, stream>>>(t1, EN2, t2);
    kC<<<dim3(144),       256, 0, stream>>>(t2, EN1, enc);
    kD<<<dim3(768),       256, 0, stream>>>(enc, DE1, u1);
    kE<<<dim3(2, 768),    256, 0, stream>>>(u1, DE2, u2);
    kF<<<dim3(64, 16, 4), 256, 0, stream>>>(u2, DE3, out);
}

// Round 2
// 279.485 us; speedup vs baseline: 1.8009x; 1.8009x over previous
//
#include <hip/hip_runtime.h>

// WaveMaskEncoder, MFMA bf16 version.
// x(16,128,128,128) --EN3/EN2/EN1--> enc(16,48,48,48) --DE1/DE2/DE3--> out.
// All contraction orders commute (distinct axes), so: one decode chain, and
// encode order chosen as (d in kA), then (w,h) in kMid; decode (r,q) in kMid,
// (p) in kF.
//
// MFMA 16x16x32 bf16 layouts (HW-verified per docs m89/m120):
//   A[m][k]: m = lane&15, k = (lane>>4)*8 + j   (8 contiguous k per lane)
//   B[k][n]: n = lane&15, k = (lane>>4)*8 + j   (n-major, k-contig storage)
//   C/D:     col = lane&15, row = (lane>>4)*4 + reg

#define LDIM 128
#define NDIM 48
#define HW   (LDIM * LDIM)     // 16384
#define L3V  (LDIM * HW)       // 2097152

typedef __bf16 bf16x8 __attribute__((ext_vector_type(8)));
typedef float  f32x4  __attribute__((ext_vector_type(4)));
typedef unsigned short u16;

// LDS row strides (u16 units); both are multiples of 8 u16 = 16 B for b128 alignment.
#define S128 136   // rows with K=128
#define S64  72    // rows with K=64

// Weight table offsets (u16 elements) inside W:
#define W_EN3T 0        // [p=48][d=128]
#define W_EN2T 6144     // [q=48][h=128]
#define W_EN1T 12288    // [r=48][w=128]
#define W_DE3T 18432    // [d=128][p=64 pad0]
#define W_DE2T 26624    // [h=128][q=64 pad0]
#define W_DE1T 34816    // [w=128][r=64 pad0]
#define W_TOT  43008

__device__ __forceinline__ u16 f2bf(float f) {   // fp32 -> bf16 RNE
    unsigned int u = __builtin_bit_cast(unsigned int, f);
    return (u16)((u + 0x7fffu + ((u >> 16) & 1u)) >> 16);
}
__device__ __forceinline__ bf16x8 frag(const u16* p) {
    return *reinterpret_cast<const bf16x8*>(p);
}
__device__ __forceinline__ f32x4 mfma16(bf16x8 a, bf16x8 b, f32x4 c) {
    return __builtin_amdgcn_mfma_f32_16x16x32_bf16(a, b, c, 0, 0, 0);
}

// ---------------------------------------------------------------- kPrep
__global__ __launch_bounds__(256) void kPrep(const float* __restrict__ EN3,
                                             const float* __restrict__ EN2,
                                             const float* __restrict__ EN1,
                                             const float* __restrict__ DE3,
                                             const float* __restrict__ DE2,
                                             const float* __restrict__ DE1,
                                             u16* __restrict__ W) {
    int i = blockIdx.x * 256 + threadIdx.x;
    if (i < 6144)       { int p = i >> 7, d = i & 127;                 W[i] = f2bf(EN3[d * 48 + p]); }
    else if (i < 12288) { int j = i - 6144;  int q = j >> 7, h = j & 127; W[i] = f2bf(EN2[h * 48 + q]); }
    else if (i < 18432) { int j = i - 12288; int r = j >> 7, w = j & 127; W[i] = f2bf(EN1[w * 48 + r]); }
    else if (i < 26624) { int j = i - 18432; int d = j >> 6, p = j & 63;  W[i] = f2bf(p < 48 ? DE3[p * 128 + d] : 0.f); }
    else if (i < 34816) { int j = i - 26624; int h = j >> 6, q = j & 63;  W[i] = f2bf(q < 48 ? DE2[q * 128 + h] : 0.f); }
    else if (i < 43008) { int j = i - 34816; int w = j >> 6, r = j & 63;  W[i] = f2bf(r < 48 ? DE1[r * 128 + w] : 0.f); }
}

// ---------------------------------------------------------------- kA
// t1[bc][p][hw] = sum_d EN3t[p][d] * x[bc][d][hw]   (bf16 out)
// grid (128 hw-tiles, 16 bc), block 256 = 4 waves; wave wv owns n-cols [wv*32, wv*32+32)
__global__ __launch_bounds__(256) void kA(const float* __restrict__ x,
                                          const u16* __restrict__ W,
                                          u16* __restrict__ t1) {
    __shared__ u16 lx[128 * S128];   // [hw][d]  (B-operand: n-major, k-contig)
    __shared__ u16 lo[48 * S128];    // [p][hw]  (output staging)
    const int bc  = blockIdx.y;
    const int hw0 = blockIdx.x * 128;
    const int t = threadIdx.x, lane = t & 63, wv = t >> 6, quad = lane >> 4;

    // A-frags (EN3t) fully in registers: 3 m-tiles x 4 k-steps
    bf16x8 afr[3][4];
    {
        const int row = lane & 15, kof = quad * 8;
        for (int m = 0; m < 3; ++m)
            for (int kk = 0; kk < 4; ++kk)
                afr[m][kk] = frag(W + W_EN3T + (m * 16 + row) * 128 + kk * 32 + kof);
    }
    // Stage x -> lx[hw][d], lanes along d so LDS writes are lane-contiguous.
    {
        const int d   = t & 127;
        const int hwg = (t >> 7) * 64;          // 0 or 64
        const float* xp = x + (size_t)bc * L3V + (size_t)d * HW + hw0 + hwg;
        for (int i = 0; i < 16; ++i) {
            float4 v = *reinterpret_cast<const float4*>(xp + i * 4);
            int n = hwg + i * 4;
            lx[(n + 0) * S128 + d] = f2bf(v.x);
            lx[(n + 1) * S128 + d] = f2bf(v.y);
            lx[(n + 2) * S128 + d] = f2bf(v.z);
            lx[(n + 3) * S128 + d] = f2bf(v.w);
        }
    }
    __syncthreads();
    // Compute: 3m x 2n accs, K=128 in 4 steps
    f32x4 acc[3][2] = {};
    {
        const int n0 = wv * 32, brow = lane & 15, bkof = quad * 8;
        for (int kk = 0; kk < 4; ++kk) {
            bf16x8 b0 = frag(lx + (n0 + brow) * S128 + kk * 32 + bkof);
            bf16x8 b1 = frag(lx + (n0 + 16 + brow) * S128 + kk * 32 + bkof);
            for (int m = 0; m < 3; ++m) {
                acc[m][0] = mfma16(afr[m][kk], b0, acc[m][0]);
                acc[m][1] = mfma16(afr[m][kk], b1, acc[m][1]);
            }
        }
    }
    // C-frags -> lo[p][hw] (disjoint region; no barrier needed before writes)
    {
        const int n0 = wv * 32, col = lane & 15;
        for (int m = 0; m < 3; ++m)
            for (int nf = 0; nf < 2; ++nf)
                for (int r = 0; r < 4; ++r) {
                    int p = m * 16 + quad * 4 + r;
                    int n = n0 + nf * 16 + col;
                    lo[p * S128 + n] = f2bf(acc[m][nf][r]);
                }
    }
    __syncthreads();
    // Coalesced b128 stores: 48x128 = 768 16B-units
    u16* op = t1 + (size_t)(bc * 48) * HW + hw0;
    for (int i = 0; i < 3; ++i) {
        int idx = t + i * 256;          // 0..767
        int p = idx >> 4, c = (idx & 15) * 8;
        *reinterpret_cast<float4*>(op + (size_t)p * HW + c) =
            *reinterpret_cast<const float4*>(lo + p * S128 + c);
    }
}

// ---------------------------------------------------------------- kMid
// Per slab (bc,p): S[h][w] (from t1) -> T1[h][r] -> E[q][r] -> U1t[w'][q] -> U2[h'][w'] (u2)
__global__ __launch_bounds__(256) void kMid(const u16* __restrict__ t1,
                                            const u16* __restrict__ W,
                                            u16* __restrict__ u2) {
    __shared__ u16 pool[26624];
    u16* lT = pool;            // [r=48][h=128] stride S128 : 6528
    u16* lE = pool + 6528;     // [q=48][r=64]  stride S64  : 3456 (ends 9984)
    u16* lO = pool;            // [h'=128][w'=128] stride S128 : 17408 (reuses lT+lE after G3)
    u16* lU = pool + 17408;    // [w'=128][q=64] stride S64 : 9216 (ends 26624)

    const int slab = blockIdx.x;                 // bc*48 + p
    const int t = threadIdx.x, lane = t & 63, wv = t >> 6, quad = lane >> 4;
    const int row = lane & 15, kof = quad * 8;
    const u16* Sg = t1 + (size_t)slab * HW;      // S[h][w], row stride 128

    // zero-fill K-padding of lE (r=48..63) and lU (q=48..63)
    for (int i = t; i < 48 * 16; i += 256)  { int q = i >> 4; lE[q * S64 + 48 + (i & 15)] = 0; }
    for (int i = t; i < 128 * 16; i += 256) { int w = i >> 4; lU[w * S64 + 48 + (i & 15)] = 0; }

    // ---- G1: T1[h][r] = sum_w S[h][w] * EN1[w][r];  wave: h-rows [wv*32, +32)
    {
        const int h0 = wv * 32;
        f32x4 acc[2][3] = {};
        for (int kk = 0; kk < 4; ++kk) {
            bf16x8 b[3];
            for (int n = 0; n < 3; ++n)
                b[n] = frag(W + W_EN1T + (n * 16 + row) * 128 + kk * 32 + kof);
            for (int m = 0; m < 2; ++m) {
                bf16x8 a = frag(Sg + (h0 + m * 16 + row) * 128 + kk * 32 + kof);
                for (int n = 0; n < 3; ++n) acc[m][n] = mfma16(a, b[n], acc[m][n]);
            }
        }
        // write lT[r][h]; 4 regs = 4 consecutive h -> packed 8B write
        for (int m = 0; m < 2; ++m)
            for (int n = 0; n < 3; ++n) {
                int r = n * 16 + row;
                int h = h0 + m * 16 + quad * 4;
                uint2 pk;
                pk.x = (unsigned)f2bf(acc[m][n][0]) | ((unsigned)f2bf(acc[m][n][1]) << 16);
                pk.y = (unsigned)f2bf(acc[m][n][2]) | ((unsigned)f2bf(acc[m][n][3]) << 16);
                *reinterpret_cast<uint2*>(lT + r * S128 + h) = pk;
            }
    }
    __syncthreads();
    // ---- G2: E[q][r] = sum_h EN2[h][q] * T1[h][r];  waves 0..2, m-tile = wv
    if (wv < 3) {
        const int q0 = wv * 16;
        f32x4 acc[3] = {};
        for (int kk = 0; kk < 4; ++kk) {
            bf16x8 a = frag(W + W_EN2T + (q0 + row) * 128 + kk * 32 + kof);
            for (int n = 0; n < 3; ++n) {
                bf16x8 b = frag(lT + (n * 16 + row) * S128 + kk * 32 + kof);
                acc[n] = mfma16(a, b, acc[n]);
            }
        }
        for (int n = 0; n < 3; ++n)
            for (int j = 0; j < 4; ++j)
                lE[(q0 + quad * 4 + j) * S64 + n * 16 + row] = f2bf(acc[n][j]);
    }
    __syncthreads();
    // ---- G3: U1t[w'][q] = sum_r DE1[r][w'] * E[q][r];  wave: w'-rows [wv*32, +32), K=64
    {
        const int w0 = wv * 32;
        f32x4 acc[2][3] = {};
        for (int kk = 0; kk < 2; ++kk) {
            bf16x8 b[3];
            for (int n = 0; n < 3; ++n)
                b[n] = frag(lE + (n * 16 + row) * S64 + kk * 32 + kof);
            for (int m = 0; m < 2; ++m) {
                bf16x8 a = frag(W + W_DE1T + (w0 + m * 16 + row) * 64 + kk * 32 + kof);
                for (int n = 0; n < 3; ++n) acc[m][n] = mfma16(a, b[n], acc[m][n]);
            }
        }
        for (int m = 0; m < 2; ++m)
            for (int n = 0; n < 3; ++n)
                for (int j = 0; j < 4; ++j)
                    lU[(w0 + m * 16 + quad * 4 + j) * S64 + n * 16 + row] = f2bf(acc[m][n][j]);
    }
    __syncthreads();
    // ---- G4: U2[h'][w'] = sum_q DE2[q][h'] * U1[q][w'];  wave 2x2 tiling, K=64
    {
        const int m0 = (wv & 1) * 64, n0 = (wv >> 1) * 64;
        f32x4 acc[4][4] = {};
        for (int kk = 0; kk < 2; ++kk) {
            bf16x8 b[4];
            for (int n = 0; n < 4; ++n)
                b[n] = frag(lU + (n0 + n * 16 + row) * S64 + kk * 32 + kof);
            for (int m = 0; m < 4; ++m) {
                bf16x8 a = frag(W + W_DE2T + (m0 + m * 16 + row) * 64 + kk * 32 + kof);
                for (int n = 0; n < 4; ++n) acc[m][n] = mfma16(a, b[n], acc[m][n]);
            }
        }
        // write lO[h'][w'] (overlaps lT/lE which are dead; lU untouched)
        for (int m = 0; m < 4; ++m)
            for (int n = 0; n < 4; ++n)
                for (int j = 0; j < 4; ++j)
                    lO[(m0 + m * 16 + quad * 4 + j) * S128 + n0 + n * 16 + row] = f2bf(acc[m][n][j]);
    }
    __syncthreads();
    // store u2 slab [h'][w'] coalesced
    u16* up = u2 + (size_t)slab * HW;
    for (int i = 0; i < 8; ++i) {
        int idx = t + i * 256;          // 0..2047
        int h = idx >> 4, c = (idx & 15) * 8;
        *reinterpret_cast<float4*>(up + h * 128 + c) =
            *reinterpret_cast<const float4*>(lO + h * S128 + c);
    }
}

// ---------------------------------------------------------------- kF
// out[bc][d][hw] = sum_p DE3[p][d] * u2[bc][p][hw]   (fp32 out), K=48 padded to 64
__global__ __launch_bounds__(256) void kF(const u16* __restrict__ u2,
                                          const u16* __restrict__ W,
                                          float* __restrict__ out) {
    __shared__ u16 lb[128 * S64];    // [hw][p64]  (B-operand layout)
    const int bc = blockIdx.y, hw0 = blockIdx.x * 128;
    const int t = threadIdx.x, lane = t & 63, wv = t >> 6, quad = lane >> 4;
    const int row = lane & 15, kof = quad * 8;
    const int m0 = (wv & 1) * 64, n0 = (wv >> 1) * 64;

    // A-frags (DE3t) in registers: 4 m-tiles x 2 k-steps
    bf16x8 afr[4][2];
    for (int m = 0; m < 4; ++m)
        for (int kk = 0; kk < 2; ++kk)
            afr[m][kk] = frag(W + W_DE3T + (m0 + m * 16 + row) * 64 + kk * 32 + kof);

    // Stage u2 -> lb[hw][p], lanes along p (contiguous LDS writes); p>=48 -> zeros
    {
        const int p   = t & 63;
        const int hwb = (t >> 6) * 32;
        const u16* sp = u2 + ((size_t)(bc * 48) + p) * HW + hw0 + hwb;
        const bool valid = p < 48;
        for (int i = 0; i < 4; ++i) {
            u16 v[8] = {0, 0, 0, 0, 0, 0, 0, 0};
            if (valid) *reinterpret_cast<float4*>(v) = *reinterpret_cast<const float4*>(sp + i * 8);
            for (int j = 0; j < 8; ++j) lb[(hwb + i * 8 + j) * S64 + p] = v[j];
        }
    }
    __syncthreads();
    f32x4 acc[4][4] = {};
    for (int kk = 0; kk < 2; ++kk) {
        bf16x8 b[4];
        for (int n = 0; n < 4; ++n)
            b[n] = frag(lb + (n0 + n * 16 + row) * S64 + kk * 32 + kof);
        for (int m = 0; m < 4; ++m)
            for (int n = 0; n < 4; ++n) acc[m][n] = mfma16(afr[m][kk], b[n], acc[m][n]);
    }
    // fp32 stores straight from C-frags (16-lane x 4B = 64B segments)
    float* ob = out + (size_t)bc * L3V + hw0;
    for (int m = 0; m < 4; ++m)
        for (int n = 0; n < 4; ++n)
            for (int j = 0; j < 4; ++j) {
                int d = m0 + m * 16 + quad * 4 + j;
                int c = n0 + n * 16 + row;
                ob[(size_t)d * HW + c] = acc[m][n][j];
            }
}

// ---------------------------------------------------------------- launch
extern "C" void kernel_launch(void* const* d_in, const int* in_sizes, int n_in,
                              void* d_out, int out_size, void* d_ws, size_t ws_size,
                              hipStream_t stream) {
    const float* x   = (const float*)d_in[0];
    const float* EN3 = (const float*)d_in[1];
    const float* EN2 = (const float*)d_in[2];
    const float* EN1 = (const float*)d_in[3];
    const float* DE3 = (const float*)d_in[4];
    const float* DE2 = (const float*)d_in[5];
    const float* DE1 = (const float*)d_in[6];
    float* out = (float*)d_out;

    // ws (bytes): t1 bf16 @0 (25165824), u2 bf16 @25165824 (25165824), W @50331648 (86016)
    u16* t1 = (u16*)d_ws;
    u16* u2 = (u16*)((char*)d_ws + 25165824);
    u16* W  = (u16*)((char*)d_ws + 50331648);

    kPrep<<<dim3(168),     256, 0, stream>>>(EN3, EN2, EN1, DE3, DE2, DE1, W);
    kA   <<<dim3(128, 16), 256, 0, stream>>>(x, W, t1);
    kMid <<<dim3(768),     256, 0, stream>>>(t1, W, u2);
    kF   <<<dim3(128, 16), 256, 0, stream>>>(u2, W, out);
}